// Round 1
// baseline (406.486 us; speedup 1.0000x reference)
//
#include <hip/hip_runtime.h>
#include <hip/hip_bf16.h>
#include <math.h>

#define B_   2
#define S_   2048
#define D_   1024
#define H_   16
#define DK_  64
#define F_   4096
#define NTOK (B_ * S_)

typedef __bf16 bf16x8 __attribute__((ext_vector_type(8)));
typedef float  f32x4  __attribute__((ext_vector_type(4)));

__device__ __forceinline__ unsigned short bf16r(float f) {
  unsigned u = __builtin_bit_cast(unsigned, f);
  u += 0x7fffu + ((u >> 16) & 1u);
  return (unsigned short)(u >> 16);
}

__device__ __forceinline__ void gload_lds16(const void* g, void* l) {
  __builtin_amdgcn_global_load_lds(
      (__attribute__((address_space(1))) void*)g,
      (__attribute__((address_space(3))) void*)l, 16, 0, 0);
}

// ---------------- weight fp32 -> bf16 ----------------
__global__ __launch_bounds__(256) void cvt_bf16_kernel(
    const float* __restrict__ in, unsigned short* __restrict__ out, int n4) {
  int i = blockIdx.x * blockDim.x + threadIdx.x;
  if (i >= n4) return;
  float4 v = reinterpret_cast<const float4*>(in)[i];
  ushort4 o;
  o.x = bf16r(v.x); o.y = bf16r(v.y); o.z = bf16r(v.z); o.w = bf16r(v.w);
  reinterpret_cast<ushort4*>(out)[i] = o;
}

// ---------------- RMSNorm (fp32 in, bf16 out) ----------------
__global__ __launch_bounds__(256) void rmsnorm_kernel(
    const float* __restrict__ x, const float* __restrict__ g,
    unsigned short* __restrict__ out) {
  int row = blockIdx.x;
  int t = threadIdx.x, lane = t & 63, w = t >> 6;
  float4 v = reinterpret_cast<const float4*>(x + (size_t)row * D_)[t];
  float ss = v.x * v.x + v.y * v.y + v.z * v.z + v.w * v.w;
#pragma unroll
  for (int d = 1; d < 64; d <<= 1) ss += __shfl_xor(ss, d);
  __shared__ float red[4];
  if (lane == 0) red[w] = ss;
  __syncthreads();
  float tot = red[0] + red[1] + red[2] + red[3];
  float rstd = rsqrtf(tot * (1.0f / D_) + 1e-5f);
  float4 gv = reinterpret_cast<const float4*>(g)[t];
  ushort4 o;
  o.x = bf16r(v.x * rstd * gv.x);
  o.y = bf16r(v.y * rstd * gv.y);
  o.z = bf16r(v.z * rstd * gv.z);
  o.w = bf16r(v.w * rstd * gv.w);
  reinterpret_cast<ushort4*>(out + (size_t)row * D_)[t] = o;
}

// ---------------- bf16 GEMM: C = A[M,K] * Bw[N,K]^T, templated epilogue ----------------
// EPI 0: bf16 store  | 1: exact GELU -> bf16 | 2: +resid -> fp32 | 3: V transposed store [b][hd][s]
template <int EPI>
__global__ __launch_bounds__(256) void gemm_bt(
    const unsigned short* __restrict__ A, const unsigned short* __restrict__ Bw,
    int M, int N, int K,
    const float* __restrict__ resid, float* __restrict__ outF,
    unsigned short* __restrict__ outB) {
  __shared__ __attribute__((aligned(16))) unsigned short lA[128 * 32];
  __shared__ __attribute__((aligned(16))) unsigned short lB[128 * 32];
  const int t = threadIdx.x, lane = t & 63, w = t >> 6;
  const int m0 = blockIdx.y * 128, n0 = blockIdx.x * 128;
  f32x4 acc[4][4] = {};
  const int nk = K >> 5;
  for (int kt = 0; kt < nk; ++kt) {
    const int k0 = kt << 5;
#pragma unroll
    for (int i = 0; i < 2; ++i) {
      int chunk = i * 256 + t;
      int row = chunk >> 2;
      int c8 = (chunk & 3) << 3;
      gload_lds16(A + (size_t)(m0 + row) * K + k0 + c8, &lA[chunk * 8]);
      gload_lds16(Bw + (size_t)(n0 + row) * K + k0 + c8, &lB[chunk * 8]);
    }
    __syncthreads();
    const int wr = (w >> 1) * 64, wc = (w & 1) * 64;
    bf16x8 af[4], bfr[4];
#pragma unroll
    for (int m = 0; m < 4; ++m)
      af[m] = *reinterpret_cast<const bf16x8*>(
          &lA[(wr + m * 16 + (lane & 15)) * 32 + (lane >> 4) * 8]);
#pragma unroll
    for (int n = 0; n < 4; ++n)
      bfr[n] = *reinterpret_cast<const bf16x8*>(
          &lB[(wc + n * 16 + (lane & 15)) * 32 + (lane >> 4) * 8]);
#pragma unroll
    for (int m = 0; m < 4; ++m)
#pragma unroll
      for (int n = 0; n < 4; ++n)
        acc[m][n] = __builtin_amdgcn_mfma_f32_16x16x32_bf16(af[m], bfr[n], acc[m][n], 0, 0, 0);
    __syncthreads();
  }
  const int rbase = m0 + (w >> 1) * 64 + (lane >> 4) * 4;
  const int cbase = n0 + (w & 1) * 64 + (lane & 15);
#pragma unroll
  for (int m = 0; m < 4; ++m) {
#pragma unroll
    for (int n = 0; n < 4; ++n) {
#pragma unroll
      for (int j = 0; j < 4; ++j) {
        int row = rbase + m * 16 + j;
        int col = cbase + n * 16;
        float v = acc[m][n][j];
        if (EPI == 0) {
          outB[(size_t)row * N + col] = bf16r(v);
        } else if (EPI == 1) {
          float gl = 0.5f * v * (1.0f + erff(v * 0.70710678118f));
          outB[(size_t)row * N + col] = bf16r(gl);
        } else if (EPI == 2) {
          outF[(size_t)row * N + col] = v + resid[(size_t)row * N + col];
        } else {
          int b = row >> 11, s = row & (S_ - 1);
          outB[((size_t)(b * D_) + col) * S_ + s] = bf16r(v);
        }
      }
    }
  }
}

// ---------------- Flash attention (causal, bf16 in/out, fp32 softmax) ----------------
// grid: (S/64, B*H); block 256 (4 waves x 16 q-rows)
__global__ __launch_bounds__(256) void attn_kernel(
    const unsigned short* __restrict__ qg, const unsigned short* __restrict__ kg,
    const unsigned short* __restrict__ vt, unsigned short* __restrict__ og) {
  __shared__ __attribute__((aligned(16))) unsigned short Kl[64 * 64];
  __shared__ __attribute__((aligned(16))) unsigned short Vl[64 * 64];
  __shared__ __attribute__((aligned(16))) unsigned short Pl[4][16 * 64];
  const int t = threadIdx.x, lane = t & 63, w = t >> 6;
  const int bh = blockIdx.y, b = bh >> 4, h = bh & 15;
  const int q0 = blockIdx.x * 64;
  const int qw = q0 + w * 16;

  bf16x8 aq[2];
  {
    const unsigned short* p =
        qg + (size_t)(b * S_ + qw + (lane & 15)) * D_ + h * DK_ + (lane >> 4) * 8;
    aq[0] = *reinterpret_cast<const bf16x8*>(p);
    aq[1] = *reinterpret_cast<const bf16x8*>(p + 32);
  }
  float mr[4] = {-1e30f, -1e30f, -1e30f, -1e30f};
  float lr[4] = {0.f, 0.f, 0.f, 0.f};
  f32x4 oacc[4] = {};

  const int nt = blockIdx.x + 1;
  for (int kt = 0; kt < nt; ++kt) {
    const int kv0 = kt * 64;
#pragma unroll
    for (int i = 0; i < 2; ++i) {
      int chunk = i * 256 + t;
      int row = chunk >> 3;
      int cg = chunk & 7;
      int sg = cg ^ (row & 7);  // pre-swizzled global source; LDS stays linear
      gload_lds16(kg + (size_t)(b * S_ + kv0 + row) * D_ + h * DK_ + sg * 8, &Kl[chunk * 8]);
      gload_lds16(vt + (size_t)(b * D_ + h * DK_ + row) * S_ + kv0 + sg * 8, &Vl[chunk * 8]);
    }
    __syncthreads();
    f32x4 sc[4] = {};
#pragma unroll
    for (int n = 0; n < 4; ++n) {
      int r = n * 16 + (lane & 15);
#pragma unroll
      for (int c = 0; c < 2; ++c) {
        int cg = (c * 4 + (lane >> 4)) ^ (r & 7);
        bf16x8 bk = *reinterpret_cast<const bf16x8*>(&Kl[r * 64 + cg * 8]);
        sc[n] = __builtin_amdgcn_mfma_f32_16x16x32_bf16(aq[c], bk, sc[n], 0, 0, 0);
      }
    }
    const bool diag = (kt == (int)blockIdx.x);
#pragma unroll
    for (int j = 0; j < 4; ++j) {
      const int qi = qw + (lane >> 4) * 4 + j;
      float mx = -1e30f;
#pragma unroll
      for (int n = 0; n < 4; ++n) {
        float s = sc[n][j] * 0.125f;
        if (diag && (kv0 + n * 16 + (lane & 15)) > qi) s = -1e30f;
        sc[n][j] = s;
        mx = fmaxf(mx, s);
      }
#pragma unroll
      for (int d = 1; d < 16; d <<= 1) mx = fmaxf(mx, __shfl_xor(mx, d));
      float mn = fmaxf(mr[j], mx);
      float sf = __expf(mr[j] - mn);
      mr[j] = mn;
      float ps = 0.f;
#pragma unroll
      for (int n = 0; n < 4; ++n) {
        float p = __expf(sc[n][j] - mn);
        sc[n][j] = p;
        ps += p;
      }
      lr[j] = lr[j] * sf + ps;
#pragma unroll
      for (int f = 0; f < 4; ++f) oacc[f][j] *= sf;
    }
    // P (fp32 C-layout) -> bf16 wave-private LDS tile, 8-col-group XOR swizzle
    unsigned short* pl = Pl[w];
#pragma unroll
    for (int n = 0; n < 4; ++n) {
#pragma unroll
      for (int j = 0; j < 4; ++j) {
        int r = (lane >> 4) * 4 + j;
        int c = n * 16 + (lane & 15);
        int cg = (c >> 3) ^ (r & 7);
        pl[r * 64 + cg * 8 + (c & 7)] = bf16r(sc[n][j]);
      }
    }
    // PV
#pragma unroll
    for (int c2 = 0; c2 < 2; ++c2) {
      int rp = lane & 15;
      int cgp = (c2 * 4 + (lane >> 4)) ^ (rp & 7);
      bf16x8 pa = *reinterpret_cast<const bf16x8*>(&pl[rp * 64 + cgp * 8]);
#pragma unroll
      for (int f = 0; f < 4; ++f) {
        int dv = f * 16 + (lane & 15);
        int cgv = (c2 * 4 + (lane >> 4)) ^ (dv & 7);
        bf16x8 vb = *reinterpret_cast<const bf16x8*>(&Vl[dv * 64 + cgv * 8]);
        oacc[f] = __builtin_amdgcn_mfma_f32_16x16x32_bf16(pa, vb, oacc[f], 0, 0, 0);
      }
    }
    __syncthreads();
  }
#pragma unroll
  for (int j = 0; j < 4; ++j) {
    float s = lr[j];
#pragma unroll
    for (int d = 1; d < 16; d <<= 1) s += __shfl_xor(s, d);
    lr[j] = 1.0f / s;
  }
#pragma unroll
  for (int f = 0; f < 4; ++f) {
#pragma unroll
    for (int j = 0; j < 4; ++j) {
      int row = b * S_ + qw + (lane >> 4) * 4 + j;
      int col = h * DK_ + f * 16 + (lane & 15);
      og[(size_t)row * D_ + col] = bf16r(oacc[f][j] * lr[j]);
    }
  }
}

// ---------------- launch ----------------
extern "C" void kernel_launch(void* const* d_in, const int* in_sizes, int n_in,
                              void* d_out, int out_size, void* d_ws, size_t ws_size,
                              hipStream_t stream) {
  const float* x  = (const float*)d_in[0];
  const float* wq = (const float*)d_in[1];
  const float* wk = (const float*)d_in[2];
  const float* wv = (const float*)d_in[3];
  const float* wo = (const float*)d_in[4];
  const float* w1 = (const float*)d_in[5];
  const float* w2 = (const float*)d_in[6];
  const float* g1 = (const float*)d_in[7];
  const float* g2 = (const float*)d_in[8];
  float* out = (float*)d_out;

  char* ws = (char*)d_ws;
  const size_t MB = 1024 * 1024;
  unsigned short* wq_b = (unsigned short*)(ws + 0 * MB);
  unsigned short* wk_b = (unsigned short*)(ws + 2 * MB);
  unsigned short* wv_b = (unsigned short*)(ws + 4 * MB);
  unsigned short* wo_b = (unsigned short*)(ws + 6 * MB);
  unsigned short* w1_b = (unsigned short*)(ws + 8 * MB);
  unsigned short* w2_b = (unsigned short*)(ws + 16 * MB);
  unsigned short* h_b  = (unsigned short*)(ws + 24 * MB);
  unsigned short* q_b  = (unsigned short*)(ws + 32 * MB);
  unsigned short* k_b  = (unsigned short*)(ws + 40 * MB);
  unsigned short* vt_b = (unsigned short*)(ws + 48 * MB);
  unsigned short* o_b  = (unsigned short*)(ws + 56 * MB);
  float*          x1   = (float*)(ws + 64 * MB);
  unsigned short* mid  = (unsigned short*)(ws + 80 * MB);

  auto cvt = [&](const float* src, unsigned short* dst, int n) {
    cvt_bf16_kernel<<<(n / 4 + 255) / 256, 256, 0, stream>>>(src, dst, n / 4);
  };
  cvt(wq, wq_b, D_ * D_);
  cvt(wk, wk_b, D_ * D_);
  cvt(wv, wv_b, D_ * D_);
  cvt(wo, wo_b, D_ * D_);
  cvt(w1, w1_b, F_ * D_);
  cvt(w2, w2_b, D_ * F_);

  rmsnorm_kernel<<<NTOK, 256, 0, stream>>>(x, g1, h_b);

  dim3 blk(256);
  gemm_bt<0><<<dim3(D_ / 128, NTOK / 128), blk, 0, stream>>>(h_b, wq_b, NTOK, D_, D_, nullptr, nullptr, q_b);
  gemm_bt<0><<<dim3(D_ / 128, NTOK / 128), blk, 0, stream>>>(h_b, wk_b, NTOK, D_, D_, nullptr, nullptr, k_b);
  gemm_bt<3><<<dim3(D_ / 128, NTOK / 128), blk, 0, stream>>>(h_b, wv_b, NTOK, D_, D_, nullptr, nullptr, vt_b);

  attn_kernel<<<dim3(S_ / 64, B_ * H_), blk, 0, stream>>>(q_b, k_b, vt_b, o_b);

  gemm_bt<2><<<dim3(D_ / 128, NTOK / 128), blk, 0, stream>>>(o_b, wo_b, NTOK, D_, D_, x, x1, nullptr);

  rmsnorm_kernel<<<NTOK, 256, 0, stream>>>(x1, g2, h_b);

  gemm_bt<1><<<dim3(F_ / 128, NTOK / 128), blk, 0, stream>>>(h_b, w1_b, NTOK, F_, D_, nullptr, nullptr, mid);
  gemm_bt<2><<<dim3(D_ / 128, NTOK / 128), blk, 0, stream>>>(mid, w2_b, NTOK, D_, F_, x1, out, nullptr);
}

// Round 2
// 325.300 us; speedup vs baseline: 1.2496x; 1.2496x over previous
//
#include <hip/hip_runtime.h>
#include <hip/hip_bf16.h>
#include <math.h>

#define B_   2
#define S_   2048
#define D_   1024
#define H_   16
#define DK_  64
#define F_   4096
#define NTOK (B_ * S_)

typedef __bf16 bf16x8 __attribute__((ext_vector_type(8)));
typedef float  f32x4  __attribute__((ext_vector_type(4)));

__device__ __forceinline__ unsigned short bf16r(float f) {
  unsigned u = __builtin_bit_cast(unsigned, f);
  u += 0x7fffu + ((u >> 16) & 1u);
  return (unsigned short)(u >> 16);
}

__device__ __forceinline__ void gload_lds16(const void* g, void* l) {
  __builtin_amdgcn_global_load_lds(
      (__attribute__((address_space(1))) void*)g,
      (__attribute__((address_space(3))) void*)l, 16, 0, 0);
}

// ---------------- all weights fp32 -> bf16, one launch ----------------
struct CvtArgs {
  const float* src[6];
  unsigned short* dst[6];
  int start[7];
};
__global__ __launch_bounds__(256) void cvt_all_kernel(CvtArgs a) {
  int i = blockIdx.x * blockDim.x + threadIdx.x;  // float4 chunk index
  if (i >= a.start[6]) return;
  int k = 0;
#pragma unroll
  for (int j = 1; j < 6; ++j)
    if (i >= a.start[j]) k = j;
  int off = i - a.start[k];
  float4 v = reinterpret_cast<const float4*>(a.src[k])[off];
  ushort4 o;
  o.x = bf16r(v.x); o.y = bf16r(v.y); o.z = bf16r(v.z); o.w = bf16r(v.w);
  reinterpret_cast<ushort4*>(a.dst[k])[off] = o;
}

// ---------------- RMSNorm (fp32 in, bf16 out) ----------------
__global__ __launch_bounds__(256) void rmsnorm_kernel(
    const float* __restrict__ x, const float* __restrict__ g,
    unsigned short* __restrict__ out) {
  int row = blockIdx.x;
  int t = threadIdx.x, lane = t & 63, w = t >> 6;
  float4 v = reinterpret_cast<const float4*>(x + (size_t)row * D_)[t];
  float ss = v.x * v.x + v.y * v.y + v.z * v.z + v.w * v.w;
#pragma unroll
  for (int d = 1; d < 64; d <<= 1) ss += __shfl_xor(ss, d);
  __shared__ float red[4];
  if (lane == 0) red[w] = ss;
  __syncthreads();
  float tot = red[0] + red[1] + red[2] + red[3];
  float rstd = rsqrtf(tot * (1.0f / D_) + 1e-5f);
  float4 gv = reinterpret_cast<const float4*>(g)[t];
  ushort4 o;
  o.x = bf16r(v.x * rstd * gv.x);
  o.y = bf16r(v.y * rstd * gv.y);
  o.z = bf16r(v.z * rstd * gv.z);
  o.w = bf16r(v.w * rstd * gv.w);
  reinterpret_cast<ushort4*>(out + (size_t)row * D_)[t] = o;
}

// ---------------- bf16 GEMM: C = A[M,K] * Bw[N,K]^T ----------------
// EPI 0: bf16 store | 1: GELU->bf16 | 2: +resid->fp32 | 4: QKV scatter (q,k,v^T)
// BN: 128 (4x4 acc/wave) or 64 (2x4 acc/wave, for narrow-N latency relief)
template <int EPI, int BN>
__global__ __launch_bounds__(256) void gemm_bt(
    const unsigned short* __restrict__ A, const unsigned short* __restrict__ Bw,
    int M, int N, int K,
    const float* __restrict__ resid, float* __restrict__ outF,
    unsigned short* __restrict__ outB, unsigned short* __restrict__ outB2,
    unsigned short* __restrict__ outB3) {
  constexpr int MR = (BN == 128) ? 4 : 2;
  __shared__ __attribute__((aligned(16))) unsigned short lA[128 * 32];
  __shared__ __attribute__((aligned(16))) unsigned short lB[BN * 32];
  const int t = threadIdx.x, lane = t & 63, w = t >> 6;
  const int m0 = blockIdx.y * 128, n0 = blockIdx.x * BN;
  const int wr = (BN == 128) ? (w >> 1) * 64 : w * 32;
  const int wc = (BN == 128) ? (w & 1) * 64 : 0;
  f32x4 acc[MR][4] = {};
  const int nk = K >> 5;
  constexpr int ITERS = (128 + BN) * 4 / 256;
  for (int kt = 0; kt < nk; ++kt) {
    const int k0 = kt << 5;
#pragma unroll
    for (int i = 0; i < ITERS; ++i) {
      int chunk = i * 256 + t;
      if (chunk < 512) {
        int row = chunk >> 2, c8 = (chunk & 3) << 3;
        gload_lds16(A + (size_t)(m0 + row) * K + k0 + c8, &lA[chunk * 8]);
      } else {
        int bc = chunk - 512, row = bc >> 2, c8 = (bc & 3) << 3;
        gload_lds16(Bw + (size_t)(n0 + row) * K + k0 + c8, &lB[bc * 8]);
      }
    }
    __syncthreads();
    bf16x8 af[MR], bfr[4];
#pragma unroll
    for (int m = 0; m < MR; ++m)
      af[m] = *reinterpret_cast<const bf16x8*>(
          &lA[(wr + m * 16 + (lane & 15)) * 32 + (lane >> 4) * 8]);
#pragma unroll
    for (int n = 0; n < 4; ++n)
      bfr[n] = *reinterpret_cast<const bf16x8*>(
          &lB[(wc + n * 16 + (lane & 15)) * 32 + (lane >> 4) * 8]);
#pragma unroll
    for (int m = 0; m < MR; ++m)
#pragma unroll
      for (int n = 0; n < 4; ++n)
        acc[m][n] = __builtin_amdgcn_mfma_f32_16x16x32_bf16(af[m], bfr[n], acc[m][n], 0, 0, 0);
    __syncthreads();
  }
  const int rbase = m0 + wr + ((lane >> 4) << 2);
  const int cbase = n0 + wc + (lane & 15);
#pragma unroll
  for (int m = 0; m < MR; ++m) {
#pragma unroll
    for (int n = 0; n < 4; ++n) {
      int col = cbase + n * 16;
#pragma unroll
      for (int j = 0; j < 4; ++j) {
        int row = rbase + m * 16 + j;
        float v = acc[m][n][j];
        if (EPI == 0) {
          outB[(size_t)row * N + col] = bf16r(v);
        } else if (EPI == 1) {
          float gl = 0.5f * v * (1.0f + erff(v * 0.70710678118f));
          outB[(size_t)row * N + col] = bf16r(gl);
        } else if (EPI == 2) {
          outF[(size_t)row * N + col] = v + resid[(size_t)row * N + col];
        } else {  // EPI 4: QKV scatter
          if (col < D_) {
            outB[(size_t)row * D_ + col] = bf16r(v);
          } else if (col < 2 * D_) {
            outB2[(size_t)row * D_ + (col - D_)] = bf16r(v);
          } else {
            int bb = row >> 11, s = row & (S_ - 1);
            outB3[((size_t)(bb * D_) + (col - 2 * D_)) * S_ + s] = bf16r(v);
          }
        }
      }
    }
  }
}

// ---------------- Flash attention (causal, swapped-QK^T, in-lane softmax) ----
// grid: (S/128, B*H); block 512 (8 waves x 16 q-rows). Heavy blocks first.
__global__ __launch_bounds__(512) void attn_kernel(
    const unsigned short* __restrict__ qg, const unsigned short* __restrict__ kg,
    const unsigned short* __restrict__ vt, unsigned short* __restrict__ og) {
  __shared__ __attribute__((aligned(16))) unsigned short Kl[64 * 64];
  __shared__ __attribute__((aligned(16))) unsigned short Vl[64 * 64];
  __shared__ __attribute__((aligned(16))) unsigned short Pl[8][16 * 64];
  const int t = threadIdx.x, lane = t & 63, w = t >> 6;
  const int lg = lane >> 4, ln = lane & 15;
  const int bh = blockIdx.y, b = bh >> 4, h = bh & 15;
  const int q0 = ((int)gridDim.x - 1 - (int)blockIdx.x) * 128;
  const int qw = q0 + w * 16;

  bf16x8 aq[2];
  {
    const unsigned short* qp =
        qg + (size_t)(b * S_ + qw + ln) * D_ + h * DK_ + lg * 8;
    aq[0] = *reinterpret_cast<const bf16x8*>(qp);
    aq[1] = *reinterpret_cast<const bf16x8*>(qp + 32);
  }
  float mr = -1e30f, lr = 0.f;  // stats for q = qw + ln (replicated over lg)
  f32x4 oacc[4] = {};
  const int dqt = qw >> 6;
  const int nt = (q0 >> 6) + 2;
  const float SCL = 0.125f * 1.44269504089f;  // 1/sqrt(dk) * log2(e)

  for (int kt = 0; kt < nt; ++kt) {
    const int kv0 = kt * 64;
    {
      int row = t >> 3, cg = t & 7, sg = cg ^ (row & 7);  // pre-swizzled source
      gload_lds16(kg + (size_t)(b * S_ + kv0 + row) * D_ + h * DK_ + sg * 8, &Kl[t * 8]);
      gload_lds16(vt + (size_t)(b * D_ + h * DK_ + row) * S_ + kv0 + sg * 8, &Vl[t * 8]);
    }
    __syncthreads();
    if (kt <= dqt) {
      // QK^T swapped: A=K rows (kv), B=Q rows (q) -> lane holds P[kv...][q=ln]
      f32x4 sc[4] = {};
#pragma unroll
      for (int n = 0; n < 4; ++n) {
        int r = n * 16 + ln;
#pragma unroll
        for (int c = 0; c < 2; ++c) {
          int cg = (c * 4 + lg) ^ (r & 7);
          bf16x8 bk = *reinterpret_cast<const bf16x8*>(&Kl[r * 64 + cg * 8]);
          sc[n] = __builtin_amdgcn_mfma_f32_16x16x32_bf16(bk, aq[c], sc[n], 0, 0, 0);
        }
      }
      const bool diag = (kt == dqt);
      const int qi = qw + ln;
      float mx = -1e30f;
#pragma unroll
      for (int n = 0; n < 4; ++n)
#pragma unroll
        for (int j = 0; j < 4; ++j) {
          float s = sc[n][j] * SCL;
          if (diag && (kv0 + n * 16 + lg * 4 + j) > qi) s = -1e30f;
          sc[n][j] = s;
          mx = fmaxf(mx, s);
        }
      mx = fmaxf(mx, __shfl_xor(mx, 16));
      mx = fmaxf(mx, __shfl_xor(mx, 32));
      float mn = fmaxf(mr, mx);
      float sf = exp2f(mr - mn);
      mr = mn;
      float ps = 0.f;
#pragma unroll
      for (int n = 0; n < 4; ++n)
#pragma unroll
        for (int j = 0; j < 4; ++j) {
          float p = exp2f(sc[n][j] - mn);
          sc[n][j] = p;
          ps += p;
        }
      ps += __shfl_xor(ps, 16);
      ps += __shfl_xor(ps, 32);
      lr = lr * sf + ps;
      // rescale O rows q = qw + lg*4 + j with that row's sf
#pragma unroll
      for (int j = 0; j < 4; ++j) {
        float sfj = __shfl(sf, lg * 4 + j);
#pragma unroll
        for (int f = 0; f < 4; ++f) oacc[f][j] *= sfj;
      }
      // P -> bf16 LDS tile [q=16][kv=64], packed b32 writes, XOR swizzle on q
      unsigned short* pl = Pl[w];
#pragma unroll
      for (int n = 0; n < 4; ++n) {
        int kvc = n * 16 + lg * 4;
        int cg = (kvc >> 3) ^ (ln & 7);
        unsigned short* dst = &pl[ln * 64 + cg * 8 + (kvc & 7)];
        unsigned p01 = (unsigned)bf16r(sc[n][0]) | ((unsigned)bf16r(sc[n][1]) << 16);
        unsigned p23 = (unsigned)bf16r(sc[n][2]) | ((unsigned)bf16r(sc[n][3]) << 16);
        *reinterpret_cast<unsigned*>(dst) = p01;
        *reinterpret_cast<unsigned*>(dst + 2) = p23;
      }
      // PV: A = P rows (q), B = V^T rows (d)
#pragma unroll
      for (int c = 0; c < 2; ++c) {
        int cgp = (c * 4 + lg) ^ (ln & 7);
        bf16x8 pa = *reinterpret_cast<const bf16x8*>(&pl[ln * 64 + cgp * 8]);
#pragma unroll
        for (int f = 0; f < 4; ++f) {
          int dv = f * 16 + ln;
          int cgv = (c * 4 + lg) ^ (dv & 7);
          bf16x8 vb = *reinterpret_cast<const bf16x8*>(&Vl[dv * 64 + cgv * 8]);
          oacc[f] = __builtin_amdgcn_mfma_f32_16x16x32_bf16(pa, vb, oacc[f], 0, 0, 0);
        }
      }
    }
    __syncthreads();
  }
#pragma unroll
  for (int j = 0; j < 4; ++j) {
    float lj = __shfl(lr, lg * 4 + j);
    float inv = 1.0f / lj;
    int row = b * S_ + qw + lg * 4 + j;
#pragma unroll
    for (int f = 0; f < 4; ++f)
      og[(size_t)row * D_ + h * DK_ + f * 16 + ln] = bf16r(oacc[f][j] * inv);
  }
}

// ---------------- launch ----------------
extern "C" void kernel_launch(void* const* d_in, const int* in_sizes, int n_in,
                              void* d_out, int out_size, void* d_ws, size_t ws_size,
                              hipStream_t stream) {
  const float* x  = (const float*)d_in[0];
  const float* wq = (const float*)d_in[1];
  const float* wk = (const float*)d_in[2];
  const float* wv = (const float*)d_in[3];
  const float* wo = (const float*)d_in[4];
  const float* w1 = (const float*)d_in[5];
  const float* w2 = (const float*)d_in[6];
  const float* g1 = (const float*)d_in[7];
  const float* g2 = (const float*)d_in[8];
  float* out = (float*)d_out;

  char* ws = (char*)d_ws;
  const size_t MB = 1024 * 1024;
  unsigned short* wqkv_b = (unsigned short*)(ws + 0 * MB);   // [3072][1024]
  unsigned short* wo_b   = (unsigned short*)(ws + 6 * MB);
  unsigned short* w1_b   = (unsigned short*)(ws + 8 * MB);
  unsigned short* w2_b   = (unsigned short*)(ws + 16 * MB);
  unsigned short* h_b    = (unsigned short*)(ws + 24 * MB);
  unsigned short* q_b    = (unsigned short*)(ws + 32 * MB);
  unsigned short* k_b    = (unsigned short*)(ws + 40 * MB);
  unsigned short* vt_b   = (unsigned short*)(ws + 48 * MB);
  unsigned short* o_b    = (unsigned short*)(ws + 56 * MB);
  float*          x1     = (float*)(ws + 64 * MB);
  unsigned short* mid    = (unsigned short*)(ws + 80 * MB);

  CvtArgs ca;
  ca.src[0] = wq; ca.dst[0] = wqkv_b;
  ca.src[1] = wk; ca.dst[1] = wqkv_b + (size_t)D_ * D_;
  ca.src[2] = wv; ca.dst[2] = wqkv_b + (size_t)2 * D_ * D_;
  ca.src[3] = wo; ca.dst[3] = wo_b;
  ca.src[4] = w1; ca.dst[4] = w1_b;
  ca.src[5] = w2; ca.dst[5] = w2_b;
  int q4 = D_ * D_ / 4, f4 = F_ * D_ / 4;
  ca.start[0] = 0;
  ca.start[1] = q4;
  ca.start[2] = 2 * q4;
  ca.start[3] = 3 * q4;
  ca.start[4] = 4 * q4;
  ca.start[5] = 4 * q4 + f4;
  ca.start[6] = 4 * q4 + 2 * f4;
  cvt_all_kernel<<<(ca.start[6] + 255) / 256, 256, 0, stream>>>(ca);

  rmsnorm_kernel<<<NTOK, 256, 0, stream>>>(x, g1, h_b);

  dim3 blk(256);
  // fused QKV: N=3072
  gemm_bt<4, 128><<<dim3(3 * D_ / 128, NTOK / 128), blk, 0, stream>>>(
      h_b, wqkv_b, NTOK, 3 * D_, D_, nullptr, nullptr, q_b, k_b, vt_b);

  attn_kernel<<<dim3(S_ / 128, B_ * H_), dim3(512), 0, stream>>>(q_b, k_b, vt_b, o_b);

  gemm_bt<2, 64><<<dim3(D_ / 64, NTOK / 128), blk, 0, stream>>>(
      o_b, wo_b, NTOK, D_, D_, x, x1, nullptr, nullptr, nullptr);

  rmsnorm_kernel<<<NTOK, 256, 0, stream>>>(x1, g2, h_b);

  gemm_bt<1, 128><<<dim3(F_ / 128, NTOK / 128), blk, 0, stream>>>(
      h_b, w1_b, NTOK, F_, D_, nullptr, nullptr, mid, nullptr, nullptr);

  gemm_bt<2, 64><<<dim3(D_ / 64, NTOK / 128), blk, 0, stream>>>(
      mid, w2_b, NTOK, D_, F_, x1, out, nullptr, nullptr, nullptr);
}